// Round 3
// baseline (111.153 us; speedup 1.0000x reference)
//
#include <hip/hip_runtime.h>

// TT-linear fp32, fully fused, zero workspace.
//
// x:     [128][8192], i = i0*256 + i1*16 + i2   (i0:32, i1:16, i2:16)
// core0: c0[o0*128 + i0*4 + r1]                 (o0:32, r1:4)  == c0[o0][k], k=i0*4+r1
// core1: c1[(r1*16+o1)*64 + i1*4 + r2]          (o1:16, r2:4)  == c1[row][j], j=i1*4+r2
// core2: c2[r2*256 + o2*16 + i2]                (o2:16)
// out:   [128][8192], o = o0*256 + o1*16 + o2
//
// y1[col=(i0,o2)][j]   = sum_i2 x[i0,i1,i2]*c2[r2,o2,i2]          (LDS)
// y2[row=(r1,o1)][col] = sum_j  c1[row][j]*y1[col][j]             (LDS)
// out[o0,o1,o2]        = sum_k  c0[o0][k]*y2[(r1,o1)][(i0,o2)] + bias
//
// Block = (t, o2-quarter q). 512 blocks x 256 thr. LDS 64 KB static.
__global__ __launch_bounds__(256, 2) void tt_fused(
    const float* __restrict__ x, const float* __restrict__ c0,
    const float* __restrict__ c1, const float* __restrict__ c2,
    const float* __restrict__ bias, float* __restrict__ out)
{
    __shared__ float smem[16384];      // 64 KB
    float* xs  = smem;                 // [0..8192): x row (dead after B)
    float* y1s = smem + 8192;          // [8192..16384): [i1(16)][col(128)][r2(4)]
    float* y2s = smem;                 // aliases xs: [k(128)][rot-o1(16)][o2l(4)]

    const int tid = threadIdx.x;
    const int b   = blockIdx.x;
    const int t   = b >> 2, q = b & 3;

    // ---- Phase A: stage x row, flat coalesced ------------------------------
    {
        const float4* xg = reinterpret_cast<const float4*>(x + t * 8192);
        float4* xl = reinterpret_cast<float4*>(xs);
#pragma unroll
        for (int m = 0; m < 8; ++m) xl[m * 256 + tid] = xg[m * 256 + tid];
    }
    __syncthreads();

    // ---- Phase B: y1[col][j] -----------------------------------------------
    {
        const int col = tid >> 1, i1h = tid & 1;
        const int i0 = col >> 2, o2 = q * 4 + (col & 3);
        // c2 rows for this o2, from global (L2-resident), held in VGPRs
        float c2v[4][16];
#pragma unroll
        for (int r2 = 0; r2 < 4; ++r2)
#pragma unroll
            for (int m = 0; m < 4; ++m) {
                float4 v = *reinterpret_cast<const float4*>(c2 + r2 * 256 + o2 * 16 + m * 4);
                c2v[r2][4 * m + 0] = v.x; c2v[r2][4 * m + 1] = v.y;
                c2v[r2][4 * m + 2] = v.z; c2v[r2][4 * m + 3] = v.w;
            }
#pragma unroll
        for (int ii = 0; ii < 8; ++ii) {
            const int i1 = i1h * 8 + ii;
            float xv[16];
#pragma unroll
            for (int m = 0; m < 4; ++m) {               // bank-rotate read order by i0
                const int mp = (m + i0) & 3;
                float4 v = *reinterpret_cast<const float4*>(xs + i0 * 256 + i1 * 16 + mp * 4);
                xv[4 * mp + 0] = v.x; xv[4 * mp + 1] = v.y;
                xv[4 * mp + 2] = v.z; xv[4 * mp + 3] = v.w;
            }
            float s[4];
#pragma unroll
            for (int r2 = 0; r2 < 4; ++r2) {
                float a = 0.f;
#pragma unroll
                for (int i2 = 0; i2 < 16; ++i2) a += xv[i2] * c2v[r2][i2];
                s[r2] = a;
            }
            *reinterpret_cast<float4*>(y1s + (i1 * 128 + col) * 4) =
                make_float4(s[0], s[1], s[2], s[3]);
        }
    }
    __syncthreads();

    // ---- Phase C: y2[row][col], wave <-> r1, c1 via uniform s_load ---------
    {
        const int lane = tid & 63;
        const int r1 = __builtin_amdgcn_readfirstlane(tid >> 6);  // wave id
        float acc[16][2];
#pragma unroll
        for (int rr = 0; rr < 16; ++rr) { acc[rr][0] = 0.f; acc[rr][1] = 0.f; }
#pragma unroll 2
        for (int jq = 0; jq < 16; ++jq) {               // jq = i1
            float4 yv0 = *reinterpret_cast<const float4*>(y1s + (jq * 128 + lane) * 4);
            float4 yv1 = *reinterpret_cast<const float4*>(y1s + (jq * 128 + 64 + lane) * 4);
#pragma unroll
            for (int rr = 0; rr < 16; ++rr) {           // rr = o1
                const int row = r1 * 16 + rr;
                float4 cq = *reinterpret_cast<const float4*>(c1 + row * 64 + jq * 4);
                acc[rr][0] += cq.x * yv0.x + cq.y * yv0.y + cq.z * yv0.z + cq.w * yv0.w;
                acc[rr][1] += cq.x * yv1.x + cq.y * yv1.y + cq.z * yv1.z + cq.w * yv1.w;
            }
        }
        // write y2s (aliases xs; xs dead since B->C barrier). o1 rotated by i0.
#pragma unroll
        for (int g = 0; g < 2; ++g) {
            const int col = g * 64 + lane;
            const int i0 = col >> 2, o2l = col & 3;
            const int k = i0 * 4 + r1;
#pragma unroll
            for (int rr = 0; rr < 16; ++rr)
                y2s[k * 64 + (((rr + i0) & 15) << 2) + o2l] = acc[rr][g];
        }
    }
    __syncthreads();

    // ---- Phase D: out = c0 x y2 + bias, c0 via uniform s_load --------------
    {
        const int cd  = tid & 63;
        const int o0g = __builtin_amdgcn_readfirstlane(tid >> 6);
        const int o1 = cd >> 2, o2l = cd & 3;
        float acc[8];
#pragma unroll
        for (int m = 0; m < 8; ++m) acc[m] = 0.f;
#pragma unroll 4
        for (int kq = 0; kq < 32; ++kq) {
            float yv[4];
#pragma unroll
            for (int dk = 0; dk < 4; ++dk) {
                const int k = kq * 4 + dk;
                yv[dk] = y2s[k * 64 + (((o1 + (k >> 2)) & 15) << 2) + o2l];
            }
#pragma unroll
            for (int m = 0; m < 8; ++m) {
                const int o0 = o0g * 8 + m;
                float4 cq = *reinterpret_cast<const float4*>(c0 + o0 * 128 + kq * 4);
                acc[m] += cq.x * yv[0] + cq.y * yv[1] + cq.z * yv[2] + cq.w * yv[3];
            }
        }
#pragma unroll
        for (int m = 0; m < 8; ++m) {
            const int o0 = o0g * 8 + m;
            const int o = o0 * 256 + o1 * 16 + q * 4 + o2l;
            out[t * 8192 + o] = acc[m] + bias[o];
        }
    }
}

extern "C" void kernel_launch(void* const* d_in, const int* in_sizes, int n_in,
                              void* d_out, int out_size, void* d_ws, size_t ws_size,
                              hipStream_t stream) {
    const float* x    = (const float*)d_in[0];
    const float* c0   = (const float*)d_in[1];
    const float* c1   = (const float*)d_in[2];
    const float* c2   = (const float*)d_in[3];
    const float* bias = (const float*)d_in[4];
    float* out = (float*)d_out;
    (void)d_ws; (void)ws_size;   // no workspace needed — all intermediates in LDS

    tt_fused<<<512, 256, 0, stream>>>(x, c0, c1, c2, bias, out);
}

// Round 4
// 104.667 us; speedup vs baseline: 1.0620x; 1.0620x over previous
//
#include <hip/hip_runtime.h>

// TT-linear fp32, fully fused, zero workspace.
//
// x:     [128][8192], i = i0*256 + i1*16 + i2   (i0:32, i1:16, i2:16)
// core0: c0[o0*128 + k], k = i0*4 + r1          (o0:32, r1:4)
// core1: c1[(r1*16+o1)*64 + j], j = i1*4 + r2   (o1:16, r2:4)
// core2: c2[r2*256 + o2*16 + i2]                (o2:16)
// out:   [128][8192], o = o0*256 + o1*16 + o2
//
// Per block (t, o2-quarter q), 512 threads (8 waves):
//   B: y1[col=(i0,o2l)][j]  = sum_i2 x[i0,i1,i2]*c2[r2,o2,i2]      (LDS y1s)
//   C: y2[k][(o1,o2l)]      = sum_j  c1[(r1,o1)][j]*y1[col][j]     (LDS y2s)
//   D: out[o0,o1,o2]        = sum_k  c0[o0][k]*y2[k][(o1,o2l)] + bias
// All coefficient (c1,c0) accesses are wave-uniform -> s_load_dwordx4.
// All register indexing is static (no runtime-indexed arrays).

__device__ __forceinline__ float dot4(float4 a, float4 b) {
    return a.x*b.x + a.y*b.y + a.z*b.z + a.w*b.w;
}

__global__ __launch_bounds__(512, 4) void tt_fused(
    const float* __restrict__ x, const float* __restrict__ c0,
    const float* __restrict__ c1, const float* __restrict__ c2,
    const float* __restrict__ bias, float* __restrict__ out)
{
    __shared__ float smem[8448];           // 33 KB
    float* y1s = smem;                     // [i1(16)][col(128)][r2(4)] = 8192 floats
    float* y2s = smem;                     // aliased: [row=(o1*4+o2l)(64)][k pad 128->132]

    const int tid = threadIdx.x;
    const int b = blockIdx.x;
    const int t = b >> 2, q = b & 3;

    // ---- Phase B: y1 (x direct from global; L2/L3-resident) ----------------
    {
        const int col = tid >> 2;                       // 0..127
        const int i1q = tid & 3;
        const int i0 = col >> 2;
        const int o2 = q * 4 + (col & 3);
        float4 c2v[4][4];
#pragma unroll
        for (int r2 = 0; r2 < 4; ++r2)
#pragma unroll
            for (int m = 0; m < 4; ++m)
                c2v[r2][m] = *reinterpret_cast<const float4*>(c2 + r2*256 + o2*16 + m*4);
        const float* xp = x + t*8192 + i0*256;
#pragma unroll
        for (int d = 0; d < 4; ++d) {
            const int i1 = i1q*4 + d;
            float4 xv0 = *reinterpret_cast<const float4*>(xp + i1*16 + 0);
            float4 xv1 = *reinterpret_cast<const float4*>(xp + i1*16 + 4);
            float4 xv2 = *reinterpret_cast<const float4*>(xp + i1*16 + 8);
            float4 xv3 = *reinterpret_cast<const float4*>(xp + i1*16 + 12);
            float s[4];
#pragma unroll
            for (int r2 = 0; r2 < 4; ++r2)
                s[r2] = dot4(xv0, c2v[r2][0]) + dot4(xv1, c2v[r2][1])
                      + dot4(xv2, c2v[r2][2]) + dot4(xv3, c2v[r2][3]);
            *reinterpret_cast<float4*>(y1s + (i1*128 + col)*4) =
                make_float4(s[0], s[1], s[2], s[3]);
        }
    }
    __syncthreads();

    // ---- Phase C: y2, wave <-> (r1, col-half); c1 via uniform s_load -------
    {
        const int lane = tid & 63;
        const int r1 = __builtin_amdgcn_readfirstlane(tid >> 7);    // 0..3
        const int g  = (tid >> 6) & 1;
        const int col = g*64 + lane;                                // 0..127
        float acc[16];
#pragma unroll
        for (int rr = 0; rr < 16; ++rr) acc[rr] = 0.f;
        const float* c1r = c1 + r1*1024;                            // 16 rows x 64
#pragma unroll 4
        for (int jq = 0; jq < 16; ++jq) {                           // jq = i1
            float4 yv = *reinterpret_cast<const float4*>(y1s + (jq*128 + col)*4);
#pragma unroll
            for (int rr = 0; rr < 16; ++rr) {                       // rr = o1
                float4 cq = *reinterpret_cast<const float4*>(c1r + rr*64 + jq*4);
                acc[rr] += dot4(cq, yv);
            }
        }
        __syncthreads();                  // everyone done reading y1s
        const int i0 = col >> 2, o2l = col & 3;
        const int k = i0*4 + r1;
#pragma unroll
        for (int rr = 0; rr < 16; ++rr)
            y2s[(rr*4 + o2l)*132 + k] = acc[rr];
    }
    __syncthreads();

    // ---- Phase D: out = c0 x y2 + bias; c0 via uniform s_load --------------
    {
        const int lane = tid & 63;
        const int w = __builtin_amdgcn_readfirstlane(tid >> 6);     // 0..7
        const int o1 = lane >> 2, o2l = lane & 3;
        float acc[4] = {0.f, 0.f, 0.f, 0.f};
        const float* yrow = y2s + lane*132;                         // row = o1*4+o2l
#pragma unroll 4
        for (int kq = 0; kq < 32; ++kq) {
            float4 yv = *reinterpret_cast<const float4*>(yrow + kq*4);
#pragma unroll
            for (int m = 0; m < 4; ++m) {
                const int o0 = w*4 + m;
                float4 cq = *reinterpret_cast<const float4*>(c0 + o0*128 + kq*4);
                acc[m] += dot4(cq, yv);
            }
        }
#pragma unroll
        for (int m = 0; m < 4; ++m) {
            const int o0 = w*4 + m;
            const int o = o0*256 + o1*16 + q*4 + o2l;
            out[t*8192 + o] = acc[m] + bias[o];
        }
    }
}

extern "C" void kernel_launch(void* const* d_in, const int* in_sizes, int n_in,
                              void* d_out, int out_size, void* d_ws, size_t ws_size,
                              hipStream_t stream) {
    const float* x    = (const float*)d_in[0];
    const float* c0   = (const float*)d_in[1];
    const float* c1   = (const float*)d_in[2];
    const float* c2   = (const float*)d_in[3];
    const float* bias = (const float*)d_in[4];
    float* out = (float*)d_out;
    (void)d_ws; (void)ws_size;    // no workspace — intermediates live in LDS

    tt_fused<<<512, 512, 0, stream>>>(x, c0, c1, c2, bias, out);
}

// Round 5
// 84.290 us; speedup vs baseline: 1.3187x; 1.2418x over previous
//
#include <hip/hip_runtime.h>

// TT-linear fp32, fully fused, zero workspace, NO SMEM (s_load) in hot loops.
//
// x:     [128][8192], i = i0*256 + i1*16 + i2   (i0:32, i1:16, i2:16)
// core0: c0[o0*128 + k], k = i0*4 + r1          (o0:32, r1:4)
// core1: c1[(r1*16+o1)*64 + j], j = i1*4 + r2   (o1:16, r2:4)
// core2: c2[r2*256 + o2*16 + i2]                (o2:16)
// out:   [128][8192], o = o0*256 + o1*16 + o2
//
// Block = (t, o2-quarter q), 512 threads. Phases:
//   B: y1[j][col=(i0,o2l)] = sum_i2 x*c2          (LDS, row pad 132)
//   C: y2[row=(o1,o2l)][k=(i0,r1)] = c1 . y1      (LDS, quad-swizzled)
//   D: out = c0 . y2 + bias                       (c0 per-lane from global/L1)
// All inner-loop operands are VGPR or in-order DS reads; c1 is staged
// transposed (c1s[j][o1*4+r1]) so C is a 4x4 outer-product register tile.

__device__ __forceinline__ float dot4(float4 a, float4 b) {
    return a.x*b.x + a.y*b.y + a.z*b.z + a.w*b.w;
}

__global__ __launch_bounds__(512, 4) void tt_fused(
    const float* __restrict__ x, const float* __restrict__ c0,
    const float* __restrict__ c1, const float* __restrict__ c2,
    const float* __restrict__ bias, float* __restrict__ out)
{
    __shared__ __align__(16) float smem[12800];    // 51.2 KB
    float* y1s = smem;               // [j(64)][col(128) pad->132]
    float* y2s = smem;               // alias: [row(64)][k-quads swizzled, 128]
    float* c1s = smem + 8448;        // [j(64)][o1*4+r1 (64)]
    float* c2s = smem + 12544;       // [(r2*4+o2l)(16)][i2(16)]

    const int tid = threadIdx.x;
    const int b = blockIdx.x;
    const int t = b >> 2, q = b & 3;

    // ---- x loads for phase B (start early; independent of staging) --------
    const int i0 = tid >> 4, i1 = tid & 15;
    const float* xp = x + t*8192 + i0*256 + i1*16;
    float4 xq0 = *reinterpret_cast<const float4*>(xp + 0);
    float4 xq1 = *reinterpret_cast<const float4*>(xp + 4);
    float4 xq2 = *reinterpret_cast<const float4*>(xp + 8);
    float4 xq3 = *reinterpret_cast<const float4*>(xp + 12);

    // ---- stage c1 transposed: c1s[j*64 + o1*4 + r1] ------------------------
    {
        const int f = tid * 8;                      // 8 consecutive src floats
        float4 a = *reinterpret_cast<const float4*>(c1 + f);
        float4 c = *reinterpret_cast<const float4*>(c1 + f + 4);
        const int rr = f >> 6, jb = f & 63;         // no carry: jb+7 <= 63
        const int dst = (rr & 15) * 4 + (rr >> 4);  // o1*4 + r1
        c1s[(jb+0)*64 + dst] = a.x;  c1s[(jb+1)*64 + dst] = a.y;
        c1s[(jb+2)*64 + dst] = a.z;  c1s[(jb+3)*64 + dst] = a.w;
        c1s[(jb+4)*64 + dst] = c.x;  c1s[(jb+5)*64 + dst] = c.y;
        c1s[(jb+6)*64 + dst] = c.z;  c1s[(jb+7)*64 + dst] = c.w;
    }
    // ---- stage c2 slice for this q: c2s[(r2*4+o2l)*16 + i2] ----------------
    if (tid < 64) {
        const int r2 = tid >> 4, o2l = (tid >> 2) & 3, m = tid & 3;
        *reinterpret_cast<float4*>(c2s + (r2*4+o2l)*16 + m*4) =
            *reinterpret_cast<const float4*>(c2 + r2*256 + (q*4+o2l)*16 + m*4);
    }
    __syncthreads();

    // ---- Phase B: y1[j = i1*4+r2][i0*4 + o2l] ------------------------------
#pragma unroll
    for (int r2 = 0; r2 < 4; ++r2) {
        float s[4];
#pragma unroll
        for (int o2l = 0; o2l < 4; ++o2l) {
            const float4* cb = reinterpret_cast<const float4*>(c2s + (r2*4+o2l)*16);
            s[o2l] = dot4(xq0, cb[0]) + dot4(xq1, cb[1])
                   + dot4(xq2, cb[2]) + dot4(xq3, cb[3]);
        }
        *reinterpret_cast<float4*>(y1s + (i1*4+r2)*132 + i0*4) =
            make_float4(s[0], s[1], s[2], s[3]);
    }
    __syncthreads();

    // ---- Phase C: 4x4 outer-product tile; both operands in-order DS --------
    const int lane = tid & 63, w = tid >> 6;
    {
        const int rq = lane >> 5, i0c = lane & 31;
        const int o1 = w*2 + rq;
        float a00=0,a01=0,a02=0,a03=0, a10=0,a11=0,a12=0,a13=0;
        float a20=0,a21=0,a22=0,a23=0, a30=0,a31=0,a32=0,a33=0;
        const float* y1p = y1s + i0c*4;
        const float* c1p = c1s + o1*4;
#pragma unroll 4
        for (int j = 0; j < 64; ++j) {
            float4 yq = *reinterpret_cast<const float4*>(y1p + j*132);
            float4 cq = *reinterpret_cast<const float4*>(c1p + j*64);
            a00 += cq.x*yq.x; a01 += cq.x*yq.y; a02 += cq.x*yq.z; a03 += cq.x*yq.w;
            a10 += cq.y*yq.x; a11 += cq.y*yq.y; a12 += cq.y*yq.z; a13 += cq.y*yq.w;
            a20 += cq.z*yq.x; a21 += cq.z*yq.y; a22 += cq.z*yq.z; a23 += cq.z*yq.w;
            a30 += cq.w*yq.x; a31 += cq.w*yq.y; a32 += cq.w*yq.z; a33 += cq.w*yq.w;
        }
        __syncthreads();                  // all y1 reads done (y2s aliases y1s)
        // y2s[row][quad kq=i0c at swizzled pos], elements = r1 0..3
        const int rot = o1 >> 1;          // row>>3, same for all 4 o2l
        const int pos = (i0c & 24) | ((i0c + rot) & 7);
        float* yb = y2s + pos*4;
        *reinterpret_cast<float4*>(yb + (o1*4+0)*128) = make_float4(a00,a10,a20,a30);
        *reinterpret_cast<float4*>(yb + (o1*4+1)*128) = make_float4(a01,a11,a21,a31);
        *reinterpret_cast<float4*>(yb + (o1*4+2)*128) = make_float4(a02,a12,a22,a32);
        *reinterpret_cast<float4*>(yb + (o1*4+3)*128) = make_float4(a03,a13,a23,a33);
    }
    __syncthreads();

    // ---- Phase D: out[o0][o1][o2l] = sum_k c0[o0][k]*y2[row][k] + bias -----
    {
        const int o0 = (w << 2) | (lane >> 4);
        const int o1d = lane & 15;
        const int rotd = o1d >> 1;                 // row>>3 for all 4 rows
        float a0=0, a1=0, a2=0, a3=0;
        const float* c0p = c0 + o0*128;            // global, L1-resident
        const float* yrow = y2s + (o1d*4)*128;
#pragma unroll 4
        for (int kq = 0; kq < 32; ++kq) {
            float4 cq = *reinterpret_cast<const float4*>(c0p + kq*4);
            const int pos = (kq & 24) | ((kq + rotd) & 7);
            const float* bb = yrow + pos*4;
            float4 y0 = *reinterpret_cast<const float4*>(bb + 0*128);
            float4 y1v = *reinterpret_cast<const float4*>(bb + 1*128);
            float4 y2v = *reinterpret_cast<const float4*>(bb + 2*128);
            float4 y3v = *reinterpret_cast<const float4*>(bb + 3*128);
            a0 += dot4(cq, y0);  a1 += dot4(cq, y1v);
            a2 += dot4(cq, y2v); a3 += dot4(cq, y3v);
        }
        const int ob = o0*256 + o1d*16 + q*4;
        float4 bq = *reinterpret_cast<const float4*>(bias + ob);
        *reinterpret_cast<float4*>(out + t*8192 + ob) =
            make_float4(a0+bq.x, a1+bq.y, a2+bq.z, a3+bq.w);
    }
}

extern "C" void kernel_launch(void* const* d_in, const int* in_sizes, int n_in,
                              void* d_out, int out_size, void* d_ws, size_t ws_size,
                              hipStream_t stream) {
    const float* x    = (const float*)d_in[0];
    const float* c0   = (const float*)d_in[1];
    const float* c1   = (const float*)d_in[2];
    const float* c2   = (const float*)d_in[3];
    const float* bias = (const float*)d_in[4];
    float* out = (float*)d_out;
    (void)d_ws; (void)ws_size;    // no workspace — intermediates live in LDS

    tt_fused<<<512, 512, 0, stream>>>(x, c0, c1, c2, bias, out);
}

// Round 6
// 82.024 us; speedup vs baseline: 1.3551x; 1.0276x over previous
//
#include <hip/hip_runtime.h>

// TT-linear fp32, fully fused, zero workspace, LDS-traffic-minimized.
//
// x:     [128][8192], i = i0*256 + i1*16 + i2   (i0:32, i1:16, i2:16)
// core0: c0[o0*128 + k], k = i0*4 + r1          (o0:32, r1:4)
// core1: c1[(r1*16+o1)*64 + j], j = i1*4 + r2   (o1:16, r2:4)
// core2: c2[r2*256 + o2*16 + i2]                (o2:16)
// out:   [128][8192], o = o0*256 + o1*16 + o2
//
// Block (t, o2-quarter q), 512 thr. B: all waves; C: waves 0-3; D: waves 4-7.
//   B: y1[j][col=(i0,o2l)] = sum_i2 x*c2                  (LDS y1s, quad-swizzled)
//   C: y2[k=(i0,r1)][dcol=(o1,o2l)] = sum_j c1'[m][j]*y1  (LDS y2s, quad-swizzled)
//      8x4 register tile (m-oct x col-quad), c1 via broadcast VMEM (L1)
//   D: out = sum_k c0[o0][k]*y2[k][dcol] + bias
//      8x4 tile (o0-oct x col-quad), K-split-4, partials reduced via LDS
// Coefficients (c0,c1,c2) come from global/L1 with <=4 distinct addrs per
// wave-instr (broadcast) -> off the LDS pipe. Quad swizzles keep every b128
// LDS access spread evenly over all 32 banks.

__device__ __forceinline__ void fma4(float4& a, float s, const float4& v) {
    a.x += s*v.x; a.y += s*v.y; a.z += s*v.z; a.w += s*v.w;
}
__device__ __forceinline__ float dot4(float4 a, float4 b) {
    return a.x*b.x + a.y*b.y + a.z*b.z + a.w*b.w;
}

__global__ __launch_bounds__(512, 4) void tt_fused(
    const float* __restrict__ x, const float* __restrict__ c0,
    const float* __restrict__ c1, const float* __restrict__ c2,
    const float* __restrict__ bias, float* __restrict__ out)
{
    __shared__ __align__(16) float smem[16384];   // 64 KB exactly
    float* y1s = smem;          // [j(64)][qc(32) at (qc+j)&31][4]      8192 words
    float* y2s = smem + 8192;   // [k(128)][dq(16) at (dq+(k>>2)+4*(k&3))&15][4]
    float* p   = smem;          // aliases y1s after C: [ks(4)][2048]

    const int tid = threadIdx.x;
    const int b = blockIdx.x;
    const int t = b >> 2, q = b & 3;

    // ---- Phase B: y1[j=(i1,r2)][col=(i0,o2l)], all 512 threads -------------
    {
        const int i0 = tid >> 4, i1 = tid & 15;
        const float* xp = x + t*8192 + i0*256 + i1*16;
        const float4 x0 = *reinterpret_cast<const float4*>(xp + 0);
        const float4 x1 = *reinterpret_cast<const float4*>(xp + 4);
        const float4 x2 = *reinterpret_cast<const float4*>(xp + 8);
        const float4 x3 = *reinterpret_cast<const float4*>(xp + 12);
#pragma unroll
        for (int r2 = 0; r2 < 4; ++r2) {
            float s[4];
#pragma unroll
            for (int o2l = 0; o2l < 4; ++o2l) {   // c2: all lanes same addr (bcast)
                const float4* cb =
                    reinterpret_cast<const float4*>(c2 + r2*256 + (q*4 + o2l)*16);
                s[o2l] = dot4(x0, cb[0]) + dot4(x1, cb[1])
                       + dot4(x2, cb[2]) + dot4(x3, cb[3]);
            }
            const int j = i1*4 + r2;
            const int pq = (i0 + j) & 31;         // quad swizzle
            *reinterpret_cast<float4*>(y1s + j*128 + pq*4) =
                make_float4(s[0], s[1], s[2], s[3]);
        }
    }
    __syncthreads();

    // ---- Phase C: waves 0-3. 8 m x 4 n tile, K=64 --------------------------
    // m = ro*8+mm <-> (o1 = 2*ro+(mm>>2), r1 = mm&3); n = co*4+nn <-> (i0=co, o2l=nn)
    if (tid < 256) {
        const int ro = tid >> 5, co = tid & 31;
        float4 acc[8];
#pragma unroll
        for (int mm = 0; mm < 8; ++mm) acc[mm] = make_float4(0.f, 0.f, 0.f, 0.f);
#pragma unroll 4
        for (int jq = 0; jq < 16; ++jq) {
            const int j0 = jq*4;
            float4 cv[8];                          // c1: 2 distinct addrs/wave (bcast)
#pragma unroll
            for (int mm = 0; mm < 8; ++mm) {
                const int r1 = mm & 3, o1 = 2*ro + (mm >> 2);
                cv[mm] = *reinterpret_cast<const float4*>(c1 + (r1*16 + o1)*64 + j0);
            }
            float4 yv[4];
#pragma unroll
            for (int jj = 0; jj < 4; ++jj) {
                const int j = j0 + jj;
                yv[jj] = *reinterpret_cast<const float4*>(y1s + j*128 + ((co + j)&31)*4);
            }
#pragma unroll
            for (int mm = 0; mm < 8; ++mm) {
                fma4(acc[mm], cv[mm].x, yv[0]);
                fma4(acc[mm], cv[mm].y, yv[1]);
                fma4(acc[mm], cv[mm].z, yv[2]);
                fma4(acc[mm], cv[mm].w, yv[3]);
            }
        }
#pragma unroll
        for (int mm = 0; mm < 8; ++mm) {
            const int r1 = mm & 3, o1 = 2*ro + (mm >> 2);
            const int k = co*4 + r1;               // i0 = co
            const int phys = (o1 + co + 4*r1) & 15;  // (dq + (k>>2) + 4*(k&3))&15
            *reinterpret_cast<float4*>(y2s + k*64 + phys*4) = acc[mm];
        }
    }
    __syncthreads();

    // ---- Phase D main: waves 4-7. 8 o0 x 4 dcol tile, K-chunk 32 -----------
    if (tid >= 256) {
        const int td = tid - 256;
        const int ks = td >> 6, o0g = (td >> 4) & 3, colq = td & 15;  // colq = o1
        float4 acc[8];
#pragma unroll
        for (int m = 0; m < 8; ++m) acc[m] = make_float4(0.f, 0.f, 0.f, 0.f);
#pragma unroll 2
        for (int kq = 0; kq < 8; ++kq) {
            const int kb = ks*32 + kq*4;
            float4 yq[4];
#pragma unroll
            for (int kk = 0; kk < 4; ++kk) {
                const int k = kb + kk;
                const int phys = (colq + ks*8 + kq + 4*kk) & 15;
                yq[kk] = *reinterpret_cast<const float4*>(y2s + k*64 + phys*4);
            }
            float4 cq[8];                          // c0: 4 distinct addrs/wave (bcast)
#pragma unroll
            for (int o0l = 0; o0l < 8; ++o0l)
                cq[o0l] = *reinterpret_cast<const float4*>(c0 + (o0g*8 + o0l)*128 + kb);
#pragma unroll
            for (int o0l = 0; o0l < 8; ++o0l) {
                fma4(acc[o0l], cq[o0l].x, yq[0]);
                fma4(acc[o0l], cq[o0l].y, yq[1]);
                fma4(acc[o0l], cq[o0l].z, yq[2]);
                fma4(acc[o0l], cq[o0l].w, yq[3]);
            }
        }
#pragma unroll
        for (int o0l = 0; o0l < 8; ++o0l) {        // partials (p aliases dead y1s)
            const int o0 = o0g*8 + o0l;
            *reinterpret_cast<float4*>(p + ks*2048 + o0*64 + colq*4) = acc[o0l];
        }
    }
    __syncthreads();

    // ---- Final: all 512. Reduce 4 partials + bias, write out ---------------
    {
        const int o0 = tid >> 4, o1 = tid & 15;
        const float4 s0 = *reinterpret_cast<const float4*>(p + 0    + tid*4);
        const float4 s1 = *reinterpret_cast<const float4*>(p + 2048 + tid*4);
        const float4 s2 = *reinterpret_cast<const float4*>(p + 4096 + tid*4);
        const float4 s3 = *reinterpret_cast<const float4*>(p + 6144 + tid*4);
        const int ob = o0*256 + o1*16 + q*4;
        const float4 bq = *reinterpret_cast<const float4*>(bias + ob);
        *reinterpret_cast<float4*>(out + t*8192 + ob) =
            make_float4(s0.x+s1.x+s2.x+s3.x + bq.x,
                        s0.y+s1.y+s2.y+s3.y + bq.y,
                        s0.z+s1.z+s2.z+s3.z + bq.z,
                        s0.w+s1.w+s2.w+s3.w + bq.w);
    }
}

extern "C" void kernel_launch(void* const* d_in, const int* in_sizes, int n_in,
                              void* d_out, int out_size, void* d_ws, size_t ws_size,
                              hipStream_t stream) {
    const float* x    = (const float*)d_in[0];
    const float* c0   = (const float*)d_in[1];
    const float* c1   = (const float*)d_in[2];
    const float* c2   = (const float*)d_in[3];
    const float* bias = (const float*)d_in[4];
    float* out = (float*)d_out;
    (void)d_ws; (void)ws_size;    // no workspace — intermediates live in LDS

    tt_fused<<<512, 512, 0, stream>>>(x, c0, c1, c2, bias, out);
}